// Round 5
// baseline (297.830 us; speedup 1.0000x reference)
//
#include <hip/hip_runtime.h>

// Focal multi-task loss, B=4194304 rows, C=8 classes, two tasks.
// R2: 115us VALUBusy=36%. R3 fast-math: 114us VALUBusy=12.7% -> latency-bound.
// R4 source-level 2-row pipeline: VGPR=28 -> compiler coalesced it away; 110us.
// R5: inline-asm loads (volatile, saddr form) + depth-3 rolling pipeline with
//     hand-counted s_waitcnt vmcnt(9/6/3/0). Compiler cannot serialize asm.

typedef float v4f __attribute__((ext_vector_type(4)));

#define B_ROWS 4194304
#define NB 1024           // blocks per task; 1024*256 threads -> 16 rows/thread
#define STRIDE (NB * 256)

#define LOG2E 1.4426950408889634f
#define LN2   0.6931471805599453f

// Issue one row's 3 loads (2x16B logits + 1x4B label). Volatile asm: pinned
// issue order, compiler cannot sink/coalesce. saddr form: uniform base in
// SGPR pair, per-lane byte offset in one VGPR.
__device__ __forceinline__ void issue_row(v4f& a, v4f& b, int& l,
                                          unsigned voff_log, const float* lbase,
                                          unsigned voff_lab, const int* labase) {
    asm volatile("global_load_dwordx4 %0, %1, %2"
                 : "=&v"(a) : "v"(voff_log), "s"(lbase));
    asm volatile("global_load_dwordx4 %0, %1, %2 offset:16"
                 : "=&v"(b) : "v"(voff_log), "s"(lbase));
    asm volatile("global_load_dword %0, %1, %2"
                 : "=&v"(l) : "v"(voff_lab), "s"(labase));
}

#define WAIT_VM(N) do { asm volatile("s_waitcnt vmcnt(" #N ")"); \
                        __builtin_amdgcn_sched_barrier(0); } while (0)

__device__ __forceinline__ float row_loss(const v4f a, const v4f b, const int lab) {
    const float x0 = a.x, x1 = a.y, x2 = a.z, x3 = a.w;
    const float x4 = b.x, x5 = b.y, x6 = b.z, x7 = b.w;

    const float m = fmaxf(fmaxf(fmaxf(x0, x1), fmaxf(x2, x3)),
                          fmaxf(fmaxf(x4, x5), fmaxf(x6, x7)));
    const float mL = m * LOG2E;
    const float e0 = __builtin_amdgcn_exp2f(__builtin_fmaf(x0, LOG2E, -mL));
    const float e1 = __builtin_amdgcn_exp2f(__builtin_fmaf(x1, LOG2E, -mL));
    const float e2 = __builtin_amdgcn_exp2f(__builtin_fmaf(x2, LOG2E, -mL));
    const float e3 = __builtin_amdgcn_exp2f(__builtin_fmaf(x3, LOG2E, -mL));
    const float e4 = __builtin_amdgcn_exp2f(__builtin_fmaf(x4, LOG2E, -mL));
    const float e5 = __builtin_amdgcn_exp2f(__builtin_fmaf(x5, LOG2E, -mL));
    const float e6 = __builtin_amdgcn_exp2f(__builtin_fmaf(x6, LOG2E, -mL));
    const float e7 = __builtin_amdgcn_exp2f(__builtin_fmaf(x7, LOG2E, -mL));
    const float s = ((e0 + e1) + (e2 + e3)) + ((e4 + e5) + (e6 + e7));

    float el = e0;
    el = (lab == 1) ? e1 : el;
    el = (lab == 2) ? e2 : el;
    el = (lab == 3) ? e3 : el;
    el = (lab == 4) ? e4 : el;
    el = (lab == 5) ? e5 : el;
    el = (lab == 6) ? e6 : el;
    el = (lab == 7) ? e7 : el;

    const float pt = el * __builtin_amdgcn_rcpf(s);
    float c = (lab == 0) ? (0.75f * LN2) : (0.25f * LN2);
    c = (lab == 1) ? (0.375f * LN2) : c;
    const float omp = 1.0f - pt;
    const float w = omp * omp;                           // (1-pt)^2
    const float lg = __builtin_amdgcn_logf(pt + 1e-8f);  // log2(pt+1e-8)
    return -(c * w) * lg;                                // -alpha*boost*w*ln(pt+1e-8)
}

__global__ __launch_bounds__(256, 8) void focal_partial_kernel(
    const float* __restrict__ logits_dir, const int* __restrict__ labels_dir,
    const float* __restrict__ logits_vol, const int* __restrict__ labels_vol,
    float* __restrict__ partials /* [2][NB] */)
{
    const int task = blockIdx.y;
    const float* __restrict__ logits = task ? logits_vol : logits_dir;
    const int*   __restrict__ labels = task ? labels_vol : labels_dir;

    const int idx = blockIdx.x * 256 + threadIdx.x;
    const unsigned voff_log = (unsigned)idx * 32u;  // byte offset, constant over rows
    const unsigned voff_lab = (unsigned)idx * 4u;

    // 4-slot rolling register file; rows cycle through slots (j & 3).
    v4f A[4], Bv[4];
    int L[4];

    // ---- prologue: issue rows 0..2 -> 9 loads outstanding ----
    issue_row(A[0], Bv[0], L[0], voff_log, logits,                       voff_lab, labels);
    issue_row(A[1], Bv[1], L[1], voff_log, logits + (size_t)STRIDE * 8,  voff_lab, labels + STRIDE);
    issue_row(A[2], Bv[2], L[2], voff_log, logits + (size_t)STRIDE * 16, voff_lab, labels + 2 * STRIDE);

    float acc = 0.0f;
    // ---- steady state: issue row j+3, wait row j's loads (leave 9 in flight),
    //      compute row j. Fully unrolled -> all slot indices compile-time.
    #pragma unroll 13
    for (int j = 0; j <= 12; ++j) {
        issue_row(A[(j + 3) & 3], Bv[(j + 3) & 3], L[(j + 3) & 3],
                  voff_log, logits + (size_t)(j + 3) * STRIDE * 8,
                  voff_lab, labels + (j + 3) * STRIDE);
        WAIT_VM(9);
        acc += row_loss(A[j & 3], Bv[j & 3], L[j & 3]);
    }
    // ---- drain: rows 13,14,15 ----
    WAIT_VM(6);
    acc += row_loss(A[13 & 3], Bv[13 & 3], L[13 & 3]);
    WAIT_VM(3);
    acc += row_loss(A[14 & 3], Bv[14 & 3], L[14 & 3]);
    WAIT_VM(0);
    acc += row_loss(A[15 & 3], Bv[15 & 3], L[15 & 3]);

    // wave (64-lane) shuffle reduce
    #pragma unroll
    for (int off = 32; off > 0; off >>= 1)
        acc += __shfl_down(acc, off);

    __shared__ float lds[4];
    const int lane = threadIdx.x & 63;
    const int wid  = threadIdx.x >> 6;
    if (lane == 0) lds[wid] = acc;
    __syncthreads();
    if (threadIdx.x == 0) {
        const float bsum = (lds[0] + lds[1]) + (lds[2] + lds[3]);
        partials[task * NB + blockIdx.x] = bsum;
    }
}

__global__ __launch_bounds__(256) void focal_final_kernel(
    const float* __restrict__ partials, float* __restrict__ out)
{
    double sd = 0.0, sv = 0.0;
    for (int k = threadIdx.x; k < NB; k += 256) {
        sd += (double)partials[k];
        sv += (double)partials[NB + k];
    }
    #pragma unroll
    for (int off = 32; off > 0; off >>= 1) {
        sd += __shfl_down(sd, off);
        sv += __shfl_down(sv, off);
    }
    __shared__ double lds[8];
    const int lane = threadIdx.x & 63;
    const int wid  = threadIdx.x >> 6;
    if (lane == 0) { lds[wid] = sd; lds[4 + wid] = sv; }
    __syncthreads();
    if (threadIdx.x == 0) {
        const double l_dir = ((lds[0] + lds[1]) + (lds[2] + lds[3])) / (double)B_ROWS;
        const double l_vol = ((lds[4] + lds[5]) + (lds[6] + lds[7])) / (double)B_ROWS;
        out[0] = (float)(l_dir + 0.5 * l_vol);  // total = 1.0*dir + 0.5*vol
        out[1] = (float)l_dir;
        out[2] = (float)l_vol;
    }
}

extern "C" void kernel_launch(void* const* d_in, const int* in_sizes, int n_in,
                              void* d_out, int out_size, void* d_ws, size_t ws_size,
                              hipStream_t stream) {
    const float* logits_dir = (const float*)d_in[0];
    const int*   labels_dir = (const int*)d_in[1];
    const float* logits_vol = (const float*)d_in[2];
    const int*   labels_vol = (const int*)d_in[3];
    float* out = (float*)d_out;
    float* partials = (float*)d_ws;  // 2*NB floats = 8 KB, fully overwritten each call

    dim3 grid(NB, 2);
    focal_partial_kernel<<<grid, 256, 0, stream>>>(logits_dir, labels_dir,
                                                   logits_vol, labels_vol, partials);
    focal_final_kernel<<<1, 256, 0, stream>>>(partials, out);
}

// Round 6
// 295.676 us; speedup vs baseline: 1.0073x; 1.0073x over previous
//
#include <hip/hip_runtime.h>

// Focal multi-task loss, B=4194304 rows, C=8 classes, two tasks.
// R2-R5 all ~110us regardless of VALU load, source pipelining, or forced
// volatile-asm vmcnt pipeline -> NOT latency/VALU/scheduling-bound.
// Shared invariant was the stride-32B half-dense gather (1 lane = 1 row).
// R6: DENSE loads - 2 lanes per row, each wave dwordx4 = 1KB contiguous
// (copy-kernel pattern, 8 fully-used lines/instr vs 16 half-used). Row
// softmax completed with 3 DPP quad_perm(1,0,3,2) pair exchanges. Both
// lanes compute identical loss; finisher divides by 2B.

typedef float v4f __attribute__((ext_vector_type(4)));

#define B_ROWS 4194304
#define NB 1024           // blocks per task; 4096 waves/task, 32 chunks/wave
#define LOG2E 1.4426950408889634f
#define LN2   0.6931471805599453f

// pair-exchange lane l <-> l^1 via DPP quad_perm [1,0,3,2] (pure VALU, no LDS)
__device__ __forceinline__ float xor1f(float x) {
    int yi = __builtin_amdgcn_update_dpp(0, __builtin_bit_cast(int, x),
                                         0xB1 /*quad_perm(1,0,3,2)*/, 0xF, 0xF, true);
    return __builtin_bit_cast(float, yi);
}

// one chunk-slot: 16B of logits (dense across wave) + this row's label
__device__ __forceinline__ void issue_chunk(v4f& q, int& lab,
                                            unsigned voff_log, unsigned voff_lab,
                                            const float* lbase, const int* labase) {
    asm volatile("global_load_dwordx4 %0, %1, %2"
                 : "=&v"(q) : "v"(voff_log), "s"(lbase));
    asm volatile("global_load_dword %0, %1, %2"
                 : "=&v"(lab) : "v"(voff_lab), "s"(labase));
}

#define WAIT_VM(N) do { asm volatile("s_waitcnt vmcnt(" #N ")"); \
                        __builtin_amdgcn_sched_barrier(0); } while (0)

// Lane holds classes [cls_base, cls_base+4) of its row; partner has the rest.
// All pair-combines are commutative -> bit-identical result in both lanes.
__device__ __forceinline__ float half_row_loss(const v4f q, const int lab,
                                               const int cls_base) {
    const float m4 = fmaxf(fmaxf(q.x, q.y), fmaxf(q.z, q.w));
    const float m  = fmaxf(m4, xor1f(m4));                 // row max over 8
    const float mL = m * LOG2E;
    const float e0 = __builtin_amdgcn_exp2f(__builtin_fmaf(q.x, LOG2E, -mL));
    const float e1 = __builtin_amdgcn_exp2f(__builtin_fmaf(q.y, LOG2E, -mL));
    const float e2 = __builtin_amdgcn_exp2f(__builtin_fmaf(q.z, LOG2E, -mL));
    const float e3 = __builtin_amdgcn_exp2f(__builtin_fmaf(q.w, LOG2E, -mL));
    const float s4 = (e0 + e1) + (e2 + e3);
    const float s  = s4 + xor1f(s4);                       // row denom over 8
    float el4 = 0.0f;                                      // e[lab] if mine else 0
    el4 = (lab == cls_base + 0) ? e0 : el4;
    el4 = (lab == cls_base + 1) ? e1 : el4;
    el4 = (lab == cls_base + 2) ? e2 : el4;
    el4 = (lab == cls_base + 3) ? e3 : el4;
    const float el = el4 + xor1f(el4);                     // e[lab]
    const float pt = el * __builtin_amdgcn_rcpf(s);
    float c = (lab == 0) ? (0.75f * LN2) : (0.25f * LN2);  // alpha_t*boost*ln2
    c = (lab == 1) ? (0.375f * LN2) : c;
    const float omp = 1.0f - pt;
    const float w = omp * omp;                             // (1-pt)^2
    const float lg = __builtin_amdgcn_logf(pt + 1e-8f);    // log2(pt+1e-8)
    return -(c * w) * lg;
}

__global__ __launch_bounds__(256, 8) void focal_partial_kernel(
    const float* __restrict__ logits_dir, const int* __restrict__ labels_dir,
    const float* __restrict__ logits_vol, const int* __restrict__ labels_vol,
    float* __restrict__ partials /* [2][NB] */)
{
    const int task = blockIdx.y;
    const float* __restrict__ logits = task ? logits_vol : logits_dir;
    const int*   __restrict__ labels = task ? labels_vol : labels_dir;

    const int tid = threadIdx.x;
    const int gid = blockIdx.x * 256 + tid;
    const int W = gid >> 6;          // global wave id, 0..4095 per task
    const int l = tid & 63;
    const int cls_base = (l & 1) * 4;
    // wave W owns 32 consecutive 1KB chunks (32 rows each): 32KB contiguous
    const unsigned voff_log0 = (unsigned)W * 32768u + (unsigned)l * 16u;
    const unsigned voff_lab0 = (unsigned)W * 4096u  + (unsigned)(l >> 1) * 4u;

    // depth-3 rolling pipeline over 4 slots (proven structure from R5)
    v4f Q[4]; int L[4];
    issue_chunk(Q[0], L[0], voff_log0,          voff_lab0,        logits, labels);
    issue_chunk(Q[1], L[1], voff_log0 + 1024u,  voff_lab0 + 128u, logits, labels);
    issue_chunk(Q[2], L[2], voff_log0 + 2048u,  voff_lab0 + 256u, logits, labels);

    float acc = 0.0f;
    #pragma unroll
    for (int j = 0; j <= 28; ++j) {
        issue_chunk(Q[(j + 3) & 3], L[(j + 3) & 3],
                    voff_log0 + (unsigned)(j + 3) * 1024u,
                    voff_lab0 + (unsigned)(j + 3) * 128u, logits, labels);
        WAIT_VM(6);                  // slots j+1..j+3 stay in flight
        acc += half_row_loss(Q[j & 3], L[j & 3], cls_base);
    }
    WAIT_VM(4); acc += half_row_loss(Q[29 & 3], L[29 & 3], cls_base);
    WAIT_VM(2); acc += half_row_loss(Q[30 & 3], L[30 & 3], cls_base);
    WAIT_VM(0); acc += half_row_loss(Q[31 & 3], L[31 & 3], cls_base);

    // wave reduce (each row counted twice -> finisher divides by 2B)
    #pragma unroll
    for (int off = 32; off > 0; off >>= 1)
        acc += __shfl_down(acc, off);

    __shared__ float lds[4];
    const int lane = threadIdx.x & 63;
    const int wid  = threadIdx.x >> 6;
    if (lane == 0) lds[wid] = acc;
    __syncthreads();
    if (threadIdx.x == 0) {
        const float bsum = (lds[0] + lds[1]) + (lds[2] + lds[3]);
        partials[task * NB + blockIdx.x] = bsum;
    }
}

__global__ __launch_bounds__(256) void focal_final_kernel(
    const float* __restrict__ partials, float* __restrict__ out)
{
    double sd = 0.0, sv = 0.0;
    for (int k = threadIdx.x; k < NB; k += 256) {
        sd += (double)partials[k];
        sv += (double)partials[NB + k];
    }
    #pragma unroll
    for (int off = 32; off > 0; off >>= 1) {
        sd += __shfl_down(sd, off);
        sv += __shfl_down(sv, off);
    }
    __shared__ double lds[8];
    const int lane = threadIdx.x & 63;
    const int wid  = threadIdx.x >> 6;
    if (lane == 0) { lds[wid] = sd; lds[4 + wid] = sv; }
    __syncthreads();
    if (threadIdx.x == 0) {
        // each row was accumulated by BOTH lanes of its pair -> divide by 2B
        const double l_dir = ((lds[0] + lds[1]) + (lds[2] + lds[3])) / (2.0 * (double)B_ROWS);
        const double l_vol = ((lds[4] + lds[5]) + (lds[6] + lds[7])) / (2.0 * (double)B_ROWS);
        out[0] = (float)(l_dir + 0.5 * l_vol);  // total = 1.0*dir + 0.5*vol
        out[1] = (float)l_dir;
        out[2] = (float)l_vol;
    }
}

extern "C" void kernel_launch(void* const* d_in, const int* in_sizes, int n_in,
                              void* d_out, int out_size, void* d_ws, size_t ws_size,
                              hipStream_t stream) {
    const float* logits_dir = (const float*)d_in[0];
    const int*   labels_dir = (const int*)d_in[1];
    const float* logits_vol = (const float*)d_in[2];
    const int*   labels_vol = (const int*)d_in[3];
    float* out = (float*)d_out;
    float* partials = (float*)d_ws;  // 2*NB floats = 8 KB, fully overwritten each call

    dim3 grid(NB, 2);
    focal_partial_kernel<<<grid, 256, 0, stream>>>(logits_dir, labels_dir,
                                                   logits_vol, labels_vol, partials);
    focal_final_kernel<<<1, 256, 0, stream>>>(partials, out);
}